// Round 1
// baseline (4770.546 us; speedup 1.0000x reference)
//
#include <hip/hip_runtime.h>
#include <math.h>

#define EMBED 768
#define HEADS 12
#define DH 64
#define DEPTH 6
#define MLP_DIM 3072
#define N_REAL 2049
#define SP 2112            // padded row count for buffers (multiple of 64)
#define NEGV (-1e9f)

// ---------------- patch embed: conv3d(stride=kernel) as per-patch dot ----------------
__global__ void patch_embed_kernel(const float* __restrict__ x,
                                   const float* __restrict__ cw,
                                   const float* __restrict__ cb,
                                   const float* __restrict__ pos,
                                   float* __restrict__ h) {
    __shared__ float patch[1024];
    const int pi = blockIdx.x;            // 0..2047
    const int d = pi >> 8, rr = (pi >> 4) & 15, cc = pi & 15;
    const int tid = threadIdx.x;          // 256 threads
    for (int i = tid; i < 1024; i += 256) {
        int kd = i >> 8, kr = (i >> 4) & 15, kc = i & 15;
        patch[i] = x[(size_t)(d * 4 + kd) * 65536 + (rr * 16 + kr) * 256 + (cc * 16 + kc)];
    }
    __syncthreads();
    const int row = 1 + pi;
    for (int e = tid; e < EMBED; e += 256) {
        const float* w = cw + (size_t)e * 1024;
        float acc = cb[e];
        #pragma unroll 8
        for (int i = 0; i < 1024; ++i) acc += w[i] * patch[i];
        h[(size_t)row * EMBED + e] = acc + pos[(size_t)row * EMBED + e];
    }
}

__global__ void cls_init_kernel(const float* __restrict__ cls,
                                const float* __restrict__ pos,
                                float* __restrict__ h) {
    int e = blockIdx.x * 256 + threadIdx.x;
    if (e < EMBED) h[e] = cls[e] + pos[e];
}

// ---------------- layernorm (one block per row, 768 = 3*256) ----------------
__global__ void ln_kernel(const float* __restrict__ in, float* __restrict__ out,
                          const float* __restrict__ w, const float* __restrict__ b,
                          int M) {
    int row = blockIdx.x;
    if (row >= M) return;
    const float* xr = in + (size_t)row * EMBED;
    int tid = threadIdx.x;
    float v0 = xr[tid], v1 = xr[tid + 256], v2 = xr[tid + 512];
    __shared__ float red[4];
    float s = v0 + v1 + v2;
    #pragma unroll
    for (int o = 32; o > 0; o >>= 1) s += __shfl_down(s, o);
    if ((tid & 63) == 0) red[tid >> 6] = s;
    __syncthreads();
    float mean = (red[0] + red[1] + red[2] + red[3]) * (1.0f / 768.0f);
    __syncthreads();
    float d0 = v0 - mean, d1 = v1 - mean, d2 = v2 - mean;
    float q2 = d0 * d0 + d1 * d1 + d2 * d2;
    #pragma unroll
    for (int o = 32; o > 0; o >>= 1) q2 += __shfl_down(q2, o);
    if ((tid & 63) == 0) red[tid >> 6] = q2;
    __syncthreads();
    float var = (red[0] + red[1] + red[2] + red[3]) * (1.0f / 768.0f);
    float rstd = 1.0f / sqrtf(var + 1e-5f);
    float* orow = out + (size_t)row * EMBED;
    orow[tid]       = d0 * rstd * w[tid]       + b[tid];
    orow[tid + 256] = d1 * rstd * w[tid + 256] + b[tid + 256];
    orow[tid + 512] = d2 * rstd * w[tid + 512] + b[tid + 512];
}

// ---------------- generic fp32 GEMM: C = [C +] act(A@B + bias) ----------------
// A:[M,K] row-major, B:[K,N] row-major. 64x64 tile, BK=16, 256 threads, 4x4/thread.
template<int ACT, bool ACCUM>
__global__ void gemm_kernel(const float* __restrict__ A, const float* __restrict__ B,
                            const float* __restrict__ bias, float* __restrict__ C,
                            int M, int N, int K) {
    __shared__ float As[16][64];
    __shared__ float Bs[16][64];
    const int tid = threadIdx.x;
    const int bx = blockIdx.x, by = blockIdx.y;
    const int tx = tid & 15, ty = tid >> 4;
    const int row0 = by * 64, col0 = bx * 64;
    float acc[4][4] = {};
    const int arow = tid >> 2;           // 0..63
    const int acol4 = (tid & 3) * 4;     // 0,4,8,12
    const int brow = tid >> 4;           // 0..15
    const int bcol4 = (tid & 15) * 4;

    for (int kt = 0; kt < K; kt += 16) {
        {
            int gr = row0 + arow;
            float4 av = (gr < M) ? *(const float4*)(A + (size_t)gr * K + kt + acol4)
                                 : make_float4(0.f, 0.f, 0.f, 0.f);
            As[acol4 + 0][arow] = av.x;
            As[acol4 + 1][arow] = av.y;
            As[acol4 + 2][arow] = av.z;
            As[acol4 + 3][arow] = av.w;
        }
        {
            float4 bv = *(const float4*)(B + (size_t)(kt + brow) * N + col0 + bcol4);
            *(float4*)&Bs[brow][bcol4] = bv;
        }
        __syncthreads();
        #pragma unroll
        for (int kk = 0; kk < 16; ++kk) {
            float4 a = *(const float4*)&As[kk][ty * 4];
            float4 b = *(const float4*)&Bs[kk][tx * 4];
            float af[4] = {a.x, a.y, a.z, a.w};
            float bf[4] = {b.x, b.y, b.z, b.w};
            #pragma unroll
            for (int i = 0; i < 4; ++i)
                #pragma unroll
                for (int j = 0; j < 4; ++j)
                    acc[i][j] += af[i] * bf[j];
        }
        __syncthreads();
    }
    #pragma unroll
    for (int i = 0; i < 4; ++i) {
        int r = row0 + ty * 4 + i;
        if (r >= M) break;
        #pragma unroll
        for (int j = 0; j < 4; ++j) {
            int c = col0 + tx * 4 + j;
            float v = acc[i][j] + bias[c];
            if (ACT == 1) v = 0.5f * v * (1.0f + erff(v * 0.70710678118654752f));
            if (ACCUM) C[(size_t)r * N + c] += v;
            else       C[(size_t)r * N + c] = v;
        }
    }
}

// ---------------- fill ----------------
__global__ void fill_kernel(float* __restrict__ p, float val, int n) {
    int i = blockIdx.x * 256 + threadIdx.x;
    if (i < n) p[i] = val;
}

// ---------------- dilated attention: one block per (branch-seg, head) ----------------
// grid.x = 36 (flattened (branch, seg) pairs with any real position), grid.y = 12.
// Each block: 128 dilated queries x 128 dilated keys dense attention.
// Writes per-branch normalized output Obr[b][p][h][d] and lse Lbr[b][p][h].
__global__ __launch_bounds__(256, 1)
void attn_kernel(const float* __restrict__ q, const float* __restrict__ k,
                 const float* __restrict__ v,
                 float* __restrict__ Obr, float* __restrict__ Lbr) {
    const int bx = blockIdx.x, hh = blockIdx.y;
    int b, n;
    if      (bx < 17) { b = 0; n = bx; }
    else if (bx < 26) { b = 1; n = bx - 17; }
    else if (bx < 31) { b = 2; n = bx - 26; }
    else if (bx < 34) { b = 3; n = bx - 31; }
    else              { b = 4; n = bx - 34; }
    const int r = 1 << b;
    const int w = 128 << b;
    const int hb = hh & (r - 1);
    const int base = n * w + hb;

    __shared__ float ks[128][64];
    __shared__ float vs[128][64];
    const int tid = threadIdx.x;
    {   // stage K,V rows (each thread: half a row of each)
        int j = tid >> 1, half = tid & 1;
        int pos = base + r * j;
        float4* kd = (float4*)&ks[j][half * 32];
        float4* vd = (float4*)&vs[j][half * 32];
        if (pos < N_REAL) {
            const float4* ksrc = (const float4*)(k + ((size_t)pos * HEADS + hh) * DH + half * 32);
            const float4* vsrc = (const float4*)(v + ((size_t)pos * HEADS + hh) * DH + half * 32);
            #pragma unroll
            for (int u = 0; u < 8; ++u) { kd[u] = ksrc[u]; vd[u] = vsrc[u]; }
        } else {
            float4 z = make_float4(0.f, 0.f, 0.f, 0.f);
            #pragma unroll
            for (int u = 0; u < 8; ++u) { kd[u] = z; vd[u] = z; }
        }
    }
    __syncthreads();

    const int qi = tid >> 1, half = tid & 1;
    const int qpos = base + r * qi;

    float qr[64];
    if (qpos < N_REAL) {
        const float4* qs = (const float4*)(q + ((size_t)qpos * HEADS + hh) * DH);
        #pragma unroll
        for (int u = 0; u < 16; ++u) {
            float4 t = qs[u];
            qr[4*u] = t.x; qr[4*u+1] = t.y; qr[4*u+2] = t.z; qr[4*u+3] = t.w;
        }
    } else {
        #pragma unroll
        for (int u = 0; u < 64; ++u) qr[u] = 0.f;
    }

    // scores for this thread's 64 keys (fully unrolled: keep s[] in registers)
    float s[64];
    const float scale = 0.125f;
    #pragma unroll
    for (int jj = 0; jj < 64; ++jj) {
        const int key = half * 64 + jj;
        const int kpos = base + r * key;
        float acc = 0.f;
        const float4* kr4 = (const float4*)&ks[key][0];
        #pragma unroll
        for (int u = 0; u < 16; ++u) {
            float4 t = kr4[u];
            acc += qr[4*u] * t.x + qr[4*u+1] * t.y + qr[4*u+2] * t.z + qr[4*u+3] * t.w;
        }
        s[jj] = (kpos < N_REAL) ? acc * scale : NEGV;
    }
    // softmax over 128 keys (partner lane tid^1 holds other half)
    float m = NEGV;
    #pragma unroll
    for (int jj = 0; jj < 64; ++jj) m = fmaxf(m, s[jj]);
    m = fmaxf(m, __shfl_xor(m, 1));
    float sum = 0.f;
    #pragma unroll
    for (int jj = 0; jj < 64; ++jj) { s[jj] = expf(s[jj] - m); sum += s[jj]; }
    sum += __shfl_xor(sum, 1);
    // PV
    float o[64];
    #pragma unroll
    for (int u = 0; u < 64; ++u) o[u] = 0.f;
    #pragma unroll
    for (int jj = 0; jj < 64; ++jj) {
        const int key = half * 64 + jj;
        const float p = s[jj];
        const float4* vr4 = (const float4*)&vs[key][0];
        #pragma unroll
        for (int u = 0; u < 16; ++u) {
            float4 t = vr4[u];
            o[4*u]   += p * t.x;
            o[4*u+1] += p * t.y;
            o[4*u+2] += p * t.z;
            o[4*u+3] += p * t.w;
        }
    }
    #pragma unroll
    for (int u = 0; u < 64; ++u) o[u] += __shfl_xor(o[u], 1);

    if (half == 0 && qpos < N_REAL) {
        float inv = 1.0f / sum;
        float* od = Obr + ((size_t)b * SP * HEADS + (size_t)qpos * HEADS + hh) * DH;
        #pragma unroll
        for (int u = 0; u < 64; ++u) od[u] = o[u] * inv;
        Lbr[((size_t)b * SP + qpos) * HEADS + hh] = m + logf(sum);
    }
}

// ---------------- branch combine: softmax over 5 branch lse weights ----------------
__global__ void combine_kernel(const float* __restrict__ Obr, const float* __restrict__ Lbr,
                               float* __restrict__ out) {
    int gid = blockIdx.x * 256 + threadIdx.x;
    if (gid >= N_REAL * EMBED) return;
    int p = gid / EMBED, e = gid - p * EMBED;
    int h = e >> 6, d = e & 63;
    float l[5];
    float mx = NEGV;
    #pragma unroll
    for (int b = 0; b < 5; ++b) {
        l[b] = Lbr[((size_t)b * SP + p) * HEADS + h];
        mx = fmaxf(mx, l[b]);
    }
    float wsum = 0.f, acc = 0.f;
    #pragma unroll
    for (int b = 0; b < 5; ++b) {
        float wt = expf(l[b] - mx);
        wsum += wt;
        acc += wt * Obr[((size_t)b * SP * HEADS + (size_t)p * HEADS + h) * DH + d];
    }
    out[(size_t)p * EMBED + e] = acc / wsum;
}

// ---------------- host orchestration ----------------
extern "C" void kernel_launch(void* const* d_in, const int* in_sizes, int n_in,
                              void* d_out, int out_size, void* d_ws, size_t ws_size,
                              hipStream_t stream) {
    const float* x      = (const float*)d_in[0];
    const float* conv_w = (const float*)d_in[1];
    const float* conv_b = (const float*)d_in[2];
    const float* cls    = (const float*)d_in[3];
    const float* pos    = (const float*)d_in[4];
    const float* ln1w   = (const float*)d_in[5];
    const float* ln1b   = (const float*)d_in[6];
    const float* wq     = (const float*)d_in[7];
    const float* bq     = (const float*)d_in[8];
    const float* wk     = (const float*)d_in[9];
    const float* bk     = (const float*)d_in[10];
    const float* wv     = (const float*)d_in[11];
    const float* bv     = (const float*)d_in[12];
    const float* wo     = (const float*)d_in[13];
    const float* bo     = (const float*)d_in[14];
    const float* ln2w   = (const float*)d_in[15];
    const float* ln2b   = (const float*)d_in[16];
    const float* w1     = (const float*)d_in[17];
    const float* b1     = (const float*)d_in[18];
    const float* w2     = (const float*)d_in[19];
    const float* b2     = (const float*)d_in[20];
    const float* lnfw   = (const float*)d_in[21];
    const float* lnfb   = (const float*)d_in[22];

    float* ws = (float*)d_ws;
    const size_t SE = (size_t)SP * EMBED;
    float* h     = ws;                ws += SE;
    float* xln   = ws;                ws += SE;
    float* q     = ws;                ws += SE;
    float* kbuf  = ws;                ws += SE;
    float* vbuf  = ws;                ws += SE;
    float* attn  = ws;                ws += SE;
    float* mid   = ws;                ws += (size_t)SP * MLP_DIM;
    float* Obr   = ws;                ws += 5 * SE;
    float* Lbr   = ws;                ws += (size_t)5 * SP * HEADS;

    // ---- embed ----
    patch_embed_kernel<<<2048, 256, 0, stream>>>(x, conv_w, conv_b, pos, h);
    cls_init_kernel<<<3, 256, 0, stream>>>(cls, pos, h);

    const dim3 g768(EMBED / 64, (N_REAL + 63) / 64);
    const dim3 gmlp(MLP_DIM / 64, (N_REAL + 63) / 64);

    for (int L = 0; L < DEPTH; ++L) {
        const float* lwq = wq + (size_t)L * EMBED * EMBED;
        const float* lwk = wk + (size_t)L * EMBED * EMBED;
        const float* lwv = wv + (size_t)L * EMBED * EMBED;
        const float* lwo = wo + (size_t)L * EMBED * EMBED;
        const float* lbq = bq + (size_t)L * EMBED;
        const float* lbk = bk + (size_t)L * EMBED;
        const float* lbv = bv + (size_t)L * EMBED;
        const float* lbo = bo + (size_t)L * EMBED;
        const float* lw1 = w1 + (size_t)L * EMBED * MLP_DIM;
        const float* lb1 = b1 + (size_t)L * MLP_DIM;
        const float* lw2 = w2 + (size_t)L * MLP_DIM * EMBED;
        const float* lb2 = b2 + (size_t)L * EMBED;

        // LN1
        ln_kernel<<<N_REAL, 256, 0, stream>>>(h, xln, ln1w + (size_t)L * EMBED,
                                              ln1b + (size_t)L * EMBED, N_REAL);
        // QKV projections
        gemm_kernel<0, false><<<g768, 256, 0, stream>>>(xln, lwq, lbq, q,    N_REAL, EMBED, EMBED);
        gemm_kernel<0, false><<<g768, 256, 0, stream>>>(xln, lwk, lbk, kbuf, N_REAL, EMBED, EMBED);
        gemm_kernel<0, false><<<g768, 256, 0, stream>>>(xln, lwv, lbv, vbuf, N_REAL, EMBED, EMBED);
        // dilated attention branches
        fill_kernel<<<((5 * SP * HEADS) + 255) / 256, 256, 0, stream>>>(Lbr, NEGV, 5 * SP * HEADS);
        attn_kernel<<<dim3(36, 12), 256, 0, stream>>>(q, kbuf, vbuf, Obr, Lbr);
        combine_kernel<<<((N_REAL * EMBED) + 255) / 256, 256, 0, stream>>>(Obr, Lbr, attn);
        // O-projection + residual
        gemm_kernel<0, true><<<g768, 256, 0, stream>>>(attn, lwo, lbo, h, N_REAL, EMBED, EMBED);
        // LN2 + MLP + residual
        ln_kernel<<<N_REAL, 256, 0, stream>>>(h, xln, ln2w + (size_t)L * EMBED,
                                              ln2b + (size_t)L * EMBED, N_REAL);
        gemm_kernel<1, false><<<gmlp, 256, 0, stream>>>(xln, lw1, lb1, mid, N_REAL, MLP_DIM, EMBED);
        gemm_kernel<0, true><<<g768, 256, 0, stream>>>(mid, lw2, lb2, h, N_REAL, EMBED, MLP_DIM);
    }

    // final LN on row 0 -> d_out (768 floats)
    ln_kernel<<<1, 256, 0, stream>>>(h, (float*)d_out, lnfw, lnfb, 1);
}

// Round 2
// 1740.130 us; speedup vs baseline: 2.7415x; 2.7415x over previous
//
#include <hip/hip_runtime.h>
#include <math.h>

#define EMBED 768
#define HEADS 12
#define DH 64
#define DEPTH 6
#define MLP_DIM 3072
#define N_REAL 2049
#define SP 2112            // fp32 buffer row padding
#define SPAD 2176          // bf16 activation row padding (17 tiles * 128)
#define NEGV (-1e9f)

typedef __attribute__((ext_vector_type(8))) short short8;
typedef __attribute__((ext_vector_type(4))) float f32x4;

__device__ __forceinline__ unsigned short f2bf(float f) {
    union { float f; unsigned u; } x; x.f = f;
    unsigned r = x.u + 0x7FFF + ((x.u >> 16) & 1);
    return (unsigned short)(r >> 16);
}
__device__ __forceinline__ float bf2f(unsigned short s) {
    union { unsigned u; float f; } x; x.u = (unsigned)s << 16;
    return x.f;
}

// ---------------- im2col: x -> patches bf16 [2048][1024] ----------------
__global__ void im2col_kernel(const float* __restrict__ x, unsigned short* __restrict__ p) {
    const int pi = blockIdx.x;            // 0..2047
    const int d = pi >> 8, rr = (pi >> 4) & 15, cc = pi & 15;
    const int t = threadIdx.x;            // 256
    #pragma unroll
    for (int u = 0; u < 4; ++u) {
        int i = u * 256 + t;              // 0..1023
        int kd = i >> 8, kr = (i >> 4) & 15, kc = i & 15;
        float v = x[(size_t)(d * 4 + kd) * 65536 + (rr * 16 + kr) * 256 + (cc * 16 + kc)];
        p[(size_t)pi * 1024 + i] = f2bf(v);
    }
}

// ---------------- elementwise fp32 -> bf16 convert ----------------
__global__ void cvt_bf16_kernel(const float* __restrict__ in, unsigned short* __restrict__ out, int n4) {
    int i = blockIdx.x * 256 + threadIdx.x;
    if (i >= n4) return;
    float4 v = ((const float4*)in)[i];
    ushort4 o;
    o.x = f2bf(v.x); o.y = f2bf(v.y); o.z = f2bf(v.z); o.w = f2bf(v.w);
    ((ushort4*)out)[i] = o;
}

// ---------------- transpose + convert: in fp32 [R][C] -> out bf16 [C][R] ----------------
__global__ void transpose_cvt_kernel(const float* __restrict__ in, unsigned short* __restrict__ out,
                                     int R, int C) {
    __shared__ float t[32][33];
    const int tx = threadIdx.x & 31, ty = threadIdx.x >> 5;   // 32 x 8
    const int c0 = blockIdx.x * 32, r0 = blockIdx.y * 32;
    #pragma unroll
    for (int i = 0; i < 4; ++i)
        t[ty + i * 8][tx] = in[(size_t)(r0 + ty + i * 8) * C + c0 + tx];
    __syncthreads();
    #pragma unroll
    for (int i = 0; i < 4; ++i)
        out[(size_t)(c0 + ty + i * 8) * R + r0 + tx] = f2bf(t[tx][ty + i * 8]);
}

// ---------------- qkv bias concat (all layers) ----------------
__global__ void concat_bias_kernel(const float* __restrict__ bq, const float* __restrict__ bk,
                                   const float* __restrict__ bv, float* __restrict__ bqkv) {
    int i = blockIdx.x * 256 + threadIdx.x;
    if (i >= DEPTH * 2304) return;
    int L = i / 2304, j = i - L * 2304;
    float v = (j < 768) ? bq[L * 768 + j] : (j < 1536) ? bk[L * 768 + j - 768] : bv[L * 768 + j - 1536];
    bqkv[i] = v;
}

__global__ void cls_init_kernel(const float* __restrict__ cls,
                                const float* __restrict__ pos,
                                float* __restrict__ h) {
    int e = blockIdx.x * 256 + threadIdx.x;
    if (e < EMBED) h[e] = cls[e] + pos[e];
}

// ---------------- layernorm: one block per row, optional bf16 output ----------------
template<bool BF>
__global__ void ln_kernel(const float* __restrict__ in, void* __restrict__ outv,
                          const float* __restrict__ w, const float* __restrict__ b,
                          int M) {
    int row = blockIdx.x;
    if (row >= M) return;
    const float* xr = in + (size_t)row * EMBED;
    int tid = threadIdx.x;
    float v0 = xr[tid], v1 = xr[tid + 256], v2 = xr[tid + 512];
    __shared__ float red[4];
    float s = v0 + v1 + v2;
    #pragma unroll
    for (int o = 32; o > 0; o >>= 1) s += __shfl_down(s, o);
    if ((tid & 63) == 0) red[tid >> 6] = s;
    __syncthreads();
    float mean = (red[0] + red[1] + red[2] + red[3]) * (1.0f / 768.0f);
    __syncthreads();
    float d0 = v0 - mean, d1 = v1 - mean, d2 = v2 - mean;
    float q2 = d0 * d0 + d1 * d1 + d2 * d2;
    #pragma unroll
    for (int o = 32; o > 0; o >>= 1) q2 += __shfl_down(q2, o);
    if ((tid & 63) == 0) red[tid >> 6] = q2;
    __syncthreads();
    float var = (red[0] + red[1] + red[2] + red[3]) * (1.0f / 768.0f);
    float rstd = 1.0f / sqrtf(var + 1e-5f);
    float o0 = d0 * rstd * w[tid]       + b[tid];
    float o1 = d1 * rstd * w[tid + 256] + b[tid + 256];
    float o2 = d2 * rstd * w[tid + 512] + b[tid + 512];
    if (BF) {
        unsigned short* orow = (unsigned short*)outv + (size_t)row * EMBED;
        orow[tid] = f2bf(o0); orow[tid + 256] = f2bf(o1); orow[tid + 512] = f2bf(o2);
    } else {
        float* orow = (float*)outv + (size_t)row * EMBED;
        orow[tid] = o0; orow[tid + 256] = o1; orow[tid + 512] = o2;
    }
}

// ---------------- bf16 MFMA GEMM ----------------
// A: bf16 [M][K] (rows padded so tile reads are in-bounds), BT: bf16 [N][K].
// C = [C +] act(A@B + bias).  MODE: 0 store f32, 1 accum f32, 2 store bf16. ACT: 0 none, 1 gelu.
// 128x128 tile, BK=32, 256 threads = 4 waves, each wave a 64x64 sub-tile.
// LDS layout: tile[row][32] with k-octet XOR swizzle ko^=(row>>1)&3 -> conflict-free b128 r/w.
template<int ACT, int MODE>
__global__ __launch_bounds__(256)
void gemm_bf16(const unsigned short* __restrict__ A, const unsigned short* __restrict__ BT,
               const float* __restrict__ bias, void* __restrict__ Cv,
               int M, int N, int K) {
    __shared__ unsigned short Al[128 * 32];
    __shared__ unsigned short Bl[128 * 32];
    const int tid = threadIdx.x;
    const int lane = tid & 63;
    const int wid = tid >> 6;
    const int wm = wid >> 1, wn = wid & 1;
    const int row0 = blockIdx.y * 128, col0 = blockIdx.x * 128;

    f32x4 acc[4][4];
    #pragma unroll
    for (int mi = 0; mi < 4; ++mi)
        #pragma unroll
        for (int ni = 0; ni < 4; ++ni)
            #pragma unroll
            for (int j = 0; j < 4; ++j) acc[mi][ni][j] = 0.0f;

    // staging indices: thread t covers 16B chunk t of each 4KB half-tile
    const int srow = tid >> 2;                 // 0..63
    const int sko = tid & 3;                   // k-octet 0..3
    const int swzk = (sko ^ ((srow >> 1) & 3)) * 8;
    const int wbase = srow * 32 + swzk;
    // fragment read indices
    const int ln15 = lane & 15;
    const int kq = lane >> 4;
    const int kswz = (kq ^ ((ln15 >> 1) & 3)) * 8;
    const int arow_base = (wm * 64 + ln15) * 32 + kswz;
    const int brow_base = (wn * 64 + ln15) * 32 + kswz;

    for (int kt = 0; kt < K; kt += 32) {
        const size_t aoff = (size_t)(row0 + srow) * K + kt + sko * 8;
        const size_t boff = (size_t)(col0 + srow) * K + kt + sko * 8;
        short8 va0 = *(const short8*)(A + aoff);
        short8 va1 = *(const short8*)(A + aoff + (size_t)64 * K);
        short8 vb0 = *(const short8*)(BT + boff);
        short8 vb1 = *(const short8*)(BT + boff + (size_t)64 * K);
        __syncthreads();   // previous iteration's ds_reads complete
        *(short8*)&Al[wbase]           = va0;
        *(short8*)&Al[wbase + 64 * 32] = va1;
        *(short8*)&Bl[wbase]           = vb0;
        *(short8*)&Bl[wbase + 64 * 32] = vb1;
        __syncthreads();
        short8 af[4], bfr[4];
        #pragma unroll
        for (int mi = 0; mi < 4; ++mi)
            af[mi] = *(const short8*)&Al[arow_base + mi * 16 * 32];
        #pragma unroll
        for (int ni = 0; ni < 4; ++ni)
            bfr[ni] = *(const short8*)&Bl[brow_base + ni * 16 * 32];
        #pragma unroll
        for (int mi = 0; mi < 4; ++mi)
            #pragma unroll
            for (int ni = 0; ni < 4; ++ni)
                acc[mi][ni] = __builtin_amdgcn_mfma_f32_16x16x32_bf16(af[mi], bfr[ni], acc[mi][ni], 0, 0, 0);
    }

    float* Cf = (float*)Cv;
    unsigned short* Cb = (unsigned short*)Cv;
    #pragma unroll
    for (int mi = 0; mi < 4; ++mi) {
        #pragma unroll
        for (int ni = 0; ni < 4; ++ni) {
            const int col = col0 + wn * 64 + ni * 16 + ln15;
            const float bb = bias[col];
            #pragma unroll
            for (int j = 0; j < 4; ++j) {
                const int row = row0 + wm * 64 + mi * 16 + kq * 4 + j;
                if (row < M) {
                    float v = acc[mi][ni][j] + bb;
                    if (ACT == 1) v = 0.5f * v * (1.0f + erff(v * 0.70710678118654752f));
                    if (MODE == 0)      Cf[(size_t)row * N + col] = v;
                    else if (MODE == 1) Cf[(size_t)row * N + col] += v;
                    else                Cb[(size_t)row * N + col] = f2bf(v);
                }
            }
        }
    }
}

// ---------------- fill ----------------
__global__ void fill_kernel(float* __restrict__ p, float val, int n) {
    int i = blockIdx.x * 256 + threadIdx.x;
    if (i < n) p[i] = val;
}

// ---------------- dilated attention (fp32 in from fused qkv, bf16 Obr out) ----------------
__global__ __launch_bounds__(256, 1)
void attn_kernel(const float* __restrict__ qkv,
                 unsigned short* __restrict__ Obr, float* __restrict__ Lbr) {
    const int bx = blockIdx.x, hh = blockIdx.y;
    int b, n;
    if      (bx < 17) { b = 0; n = bx; }
    else if (bx < 26) { b = 1; n = bx - 17; }
    else if (bx < 31) { b = 2; n = bx - 26; }
    else if (bx < 34) { b = 3; n = bx - 31; }
    else              { b = 4; n = bx - 34; }
    const int r = 1 << b;
    const int w = 128 << b;
    const int hb = hh & (r - 1);
    const int base = n * w + hb;

    __shared__ float ks[128][64];
    __shared__ float vs[128][64];
    const int tid = threadIdx.x;
    {
        int j = tid >> 1, hf = tid & 1;
        int pos = base + r * j;
        float4* kd = (float4*)&ks[j][hf * 32];
        float4* vd = (float4*)&vs[j][hf * 32];
        if (pos < N_REAL) {
            const float* kp = qkv + (size_t)pos * 2304 + 768  + hh * 64 + hf * 32;
            const float* vp = qkv + (size_t)pos * 2304 + 1536 + hh * 64 + hf * 32;
            #pragma unroll
            for (int u = 0; u < 8; ++u) { kd[u] = ((const float4*)kp)[u]; vd[u] = ((const float4*)vp)[u]; }
        } else {
            float4 z = make_float4(0.f, 0.f, 0.f, 0.f);
            #pragma unroll
            for (int u = 0; u < 8; ++u) { kd[u] = z; vd[u] = z; }
        }
    }
    __syncthreads();

    const int qi = tid >> 1, hf = tid & 1;
    const int qpos = base + r * qi;

    float qr[64];
    if (qpos < N_REAL) {
        const float4* qs = (const float4*)(qkv + (size_t)qpos * 2304 + hh * 64);
        #pragma unroll
        for (int u = 0; u < 16; ++u) {
            float4 t = qs[u];
            qr[4*u] = t.x; qr[4*u+1] = t.y; qr[4*u+2] = t.z; qr[4*u+3] = t.w;
        }
    } else {
        #pragma unroll
        for (int u = 0; u < 64; ++u) qr[u] = 0.f;
    }

    float s[64];
    const float scale = 0.125f;
    #pragma unroll
    for (int jj = 0; jj < 64; ++jj) {
        const int key = hf * 64 + jj;
        const int kpos = base + r * key;
        float acc = 0.f;
        const float4* kr4 = (const float4*)&ks[key][0];
        #pragma unroll
        for (int u = 0; u < 16; ++u) {
            float4 t = kr4[u];
            acc += qr[4*u] * t.x + qr[4*u+1] * t.y + qr[4*u+2] * t.z + qr[4*u+3] * t.w;
        }
        s[jj] = (kpos < N_REAL) ? acc * scale : NEGV;
    }
    float m = NEGV;
    #pragma unroll
    for (int jj = 0; jj < 64; ++jj) m = fmaxf(m, s[jj]);
    m = fmaxf(m, __shfl_xor(m, 1));
    float sum = 0.f;
    #pragma unroll
    for (int jj = 0; jj < 64; ++jj) { s[jj] = expf(s[jj] - m); sum += s[jj]; }
    sum += __shfl_xor(sum, 1);
    float o[64];
    #pragma unroll
    for (int u = 0; u < 64; ++u) o[u] = 0.f;
    #pragma unroll
    for (int jj = 0; jj < 64; ++jj) {
        const int key = hf * 64 + jj;
        const float p = s[jj];
        const float4* vr4 = (const float4*)&vs[key][0];
        #pragma unroll
        for (int u = 0; u < 16; ++u) {
            float4 t = vr4[u];
            o[4*u]   += p * t.x;
            o[4*u+1] += p * t.y;
            o[4*u+2] += p * t.z;
            o[4*u+3] += p * t.w;
        }
    }
    #pragma unroll
    for (int u = 0; u < 64; ++u) o[u] += __shfl_xor(o[u], 1);

    if (hf == 0 && qpos < N_REAL) {
        float inv = 1.0f / sum;
        unsigned short* od = Obr + ((size_t)b * N_REAL + qpos) * EMBED + hh * 64;
        #pragma unroll
        for (int u = 0; u < 64; ++u) od[u] = f2bf(o[u] * inv);
        Lbr[((size_t)b * SP + qpos) * HEADS + hh] = m + logf(sum);
    }
}

// ---------------- branch combine -> bf16 ----------------
__global__ void combine_kernel(const unsigned short* __restrict__ Obr, const float* __restrict__ Lbr,
                               unsigned short* __restrict__ out) {
    int gid = blockIdx.x * 256 + threadIdx.x;
    if (gid >= N_REAL * EMBED) return;
    int p = gid / EMBED, e = gid - p * EMBED;
    int h = e >> 6;
    float l[5];
    float mx = NEGV;
    #pragma unroll
    for (int b = 0; b < 5; ++b) {
        l[b] = Lbr[((size_t)b * SP + p) * HEADS + h];
        mx = fmaxf(mx, l[b]);
    }
    float wsum = 0.f, acc = 0.f;
    #pragma unroll
    for (int b = 0; b < 5; ++b) {
        float wt = expf(l[b] - mx);
        wsum += wt;
        acc += wt * bf2f(Obr[((size_t)b * N_REAL + p) * EMBED + e]);
    }
    out[(size_t)p * EMBED + e] = f2bf(acc / wsum);
}

// ---------------- host orchestration ----------------
extern "C" void kernel_launch(void* const* d_in, const int* in_sizes, int n_in,
                              void* d_out, int out_size, void* d_ws, size_t ws_size,
                              hipStream_t stream) {
    const float* x      = (const float*)d_in[0];
    const float* conv_w = (const float*)d_in[1];
    const float* conv_b = (const float*)d_in[2];
    const float* cls    = (const float*)d_in[3];
    const float* pos    = (const float*)d_in[4];
    const float* ln1w   = (const float*)d_in[5];
    const float* ln1b   = (const float*)d_in[6];
    const float* wq     = (const float*)d_in[7];
    const float* bq     = (const float*)d_in[8];
    const float* wk     = (const float*)d_in[9];
    const float* bk     = (const float*)d_in[10];
    const float* wv     = (const float*)d_in[11];
    const float* bv     = (const float*)d_in[12];
    const float* wo     = (const float*)d_in[13];
    const float* bo     = (const float*)d_in[14];
    const float* ln2w   = (const float*)d_in[15];
    const float* ln2b   = (const float*)d_in[16];
    const float* w1     = (const float*)d_in[17];
    const float* b1     = (const float*)d_in[18];
    const float* w2     = (const float*)d_in[19];
    const float* b2     = (const float*)d_in[20];
    const float* lnfw   = (const float*)d_in[21];
    const float* lnfb   = (const float*)d_in[22];

    float* ws = (float*)d_ws;
    // fp32 buffers
    float* h     = ws;  ws += (size_t)SP * EMBED;            // residual stream
    float* qkv   = ws;  ws += (size_t)SP * 2304;             // fused q|k|v
    float* Lbr   = ws;  ws += (size_t)5 * SP * HEADS;
    float* bqkv  = ws;  ws += (size_t)DEPTH * 2304;
    // bf16 buffers (ushort)
    unsigned short* xln_bf   = (unsigned short*)ws;  ws += (size_t)SPAD * EMBED / 2;
    unsigned short* attn_bf  = (unsigned short*)ws;  ws += (size_t)SPAD * EMBED / 2;
    unsigned short* mid_bf   = (unsigned short*)ws;  ws += (size_t)SPAD * MLP_DIM / 2;
    unsigned short* patch_bf = (unsigned short*)ws;  ws += (size_t)2048 * 1024 / 2;
    unsigned short* convwT   = (unsigned short*)ws;  ws += (size_t)EMBED * 1024 / 2;
    unsigned short* Obr      = (unsigned short*)ws;  ws += (size_t)5 * N_REAL * EMBED / 2 + 64;
    unsigned short* wqkvT    = (unsigned short*)ws;  ws += (size_t)2304 * EMBED / 2;
    unsigned short* woT      = (unsigned short*)ws;  ws += (size_t)EMBED * EMBED / 2;
    unsigned short* w1T      = (unsigned short*)ws;  ws += (size_t)MLP_DIM * EMBED / 2;
    unsigned short* w2T      = (unsigned short*)ws;  ws += (size_t)EMBED * MLP_DIM / 2;

    // ---- embed ----
    im2col_kernel<<<2048, 256, 0, stream>>>(x, patch_bf);
    cvt_bf16_kernel<<<(EMBED * 1024 / 4 + 255) / 256, 256, 0, stream>>>(conv_w, convwT, EMBED * 1024 / 4);
    concat_bias_kernel<<<(DEPTH * 2304 + 255) / 256, 256, 0, stream>>>(bq, bk, bv, bqkv);
    cls_init_kernel<<<3, 256, 0, stream>>>(cls, pos, h);
    hipMemcpyAsync(h + EMBED, pos + EMBED, (size_t)2048 * EMBED * sizeof(float),
                   hipMemcpyDeviceToDevice, stream);
    // patch GEMM: h(rows 1..2048) += patches @ conv_w^T + conv_b
    gemm_bf16<0, 1><<<dim3(6, 16), 256, 0, stream>>>(patch_bf, convwT, conv_b,
                                                     h + EMBED, 2048, EMBED, 1024);

    for (int L = 0; L < DEPTH; ++L) {
        const size_t EE = (size_t)EMBED * EMBED;
        const size_t EM = (size_t)EMBED * MLP_DIM;
        // weight transposes for this layer
        transpose_cvt_kernel<<<dim3(24, 24), 256, 0, stream>>>(wq + L * EE, wqkvT,            EMBED, EMBED);
        transpose_cvt_kernel<<<dim3(24, 24), 256, 0, stream>>>(wk + L * EE, wqkvT + EE,       EMBED, EMBED);
        transpose_cvt_kernel<<<dim3(24, 24), 256, 0, stream>>>(wv + L * EE, wqkvT + 2 * EE,   EMBED, EMBED);
        transpose_cvt_kernel<<<dim3(24, 24), 256, 0, stream>>>(wo + L * EE, woT,              EMBED, EMBED);
        transpose_cvt_kernel<<<dim3(96, 24), 256, 0, stream>>>(w1 + L * EM, w1T,              EMBED, MLP_DIM);
        transpose_cvt_kernel<<<dim3(24, 96), 256, 0, stream>>>(w2 + L * EM, w2T,              MLP_DIM, EMBED);

        // LN1 -> bf16
        ln_kernel<true><<<N_REAL, 256, 0, stream>>>(h, xln_bf, ln1w + (size_t)L * EMBED,
                                                    ln1b + (size_t)L * EMBED, N_REAL);
        // fused QKV
        gemm_bf16<0, 0><<<dim3(18, 17), 256, 0, stream>>>(xln_bf, wqkvT, bqkv + (size_t)L * 2304,
                                                          qkv, N_REAL, 2304, EMBED);
        // dilated attention
        fill_kernel<<<((5 * SP * HEADS) + 255) / 256, 256, 0, stream>>>(Lbr, NEGV, 5 * SP * HEADS);
        attn_kernel<<<dim3(36, 12), 256, 0, stream>>>(qkv, Obr, Lbr);
        combine_kernel<<<((N_REAL * EMBED) + 255) / 256, 256, 0, stream>>>(Obr, Lbr, attn_bf);
        // O-projection + residual
        gemm_bf16<0, 1><<<dim3(6, 17), 256, 0, stream>>>(attn_bf, woT, bo + (size_t)L * EMBED,
                                                         h, N_REAL, EMBED, EMBED);
        // LN2 + MLP + residual
        ln_kernel<true><<<N_REAL, 256, 0, stream>>>(h, xln_bf, ln2w + (size_t)L * EMBED,
                                                    ln2b + (size_t)L * EMBED, N_REAL);
        gemm_bf16<1, 2><<<dim3(24, 17), 256, 0, stream>>>(xln_bf, w1T, b1 + (size_t)L * MLP_DIM,
                                                          mid_bf, N_REAL, MLP_DIM, EMBED);
        gemm_bf16<0, 1><<<dim3(6, 17), 256, 0, stream>>>(mid_bf, w2T, b2 + (size_t)L * EMBED,
                                                         h, N_REAL, EMBED, MLP_DIM);
    }

    // final LN on row 0 -> d_out (768 fp32)
    ln_kernel<false><<<1, 256, 0, stream>>>(h, (float*)d_out, lnfw, lnfb, 1);
}

// Round 3
// 1696.561 us; speedup vs baseline: 2.8119x; 1.0257x over previous
//
#include <hip/hip_runtime.h>
#include <math.h>

#define EMBED 768
#define HEADS 12
#define DH 64
#define DEPTH 6
#define MLP_DIM 3072
#define N_REAL 2049
#define SP 2112            // fp32 buffer row padding
#define SPAD 2176          // bf16 activation row padding (17 tiles * 128)
#define NEGV (-1e9f)

typedef __attribute__((ext_vector_type(8))) short short8;
typedef __attribute__((ext_vector_type(4))) float f32x4;

__device__ __forceinline__ unsigned short f2bf(float f) {
    union { float f; unsigned u; } x; x.f = f;
    unsigned r = x.u + 0x7FFF + ((x.u >> 16) & 1);
    return (unsigned short)(r >> 16);
}
__device__ __forceinline__ float bf2f(unsigned short s) {
    union { unsigned u; float f; } x; x.u = (unsigned)s << 16;
    return x.f;
}

// async global->LDS, 16B per lane; LDS dest = wave-uniform base + lane*16
__device__ __forceinline__ void gload16(const unsigned short* g, unsigned short* l) {
    __builtin_amdgcn_global_load_lds(
        (const __attribute__((address_space(1))) void*)g,
        (__attribute__((address_space(3))) void*)l, 16, 0, 0);
}

// ---------------- im2col: x -> patches bf16 [2048][1024] ----------------
__global__ void im2col_kernel(const float* __restrict__ x, unsigned short* __restrict__ p) {
    const int pi = blockIdx.x;            // 0..2047
    const int d = pi >> 8, rr = (pi >> 4) & 15, cc = pi & 15;
    const int t = threadIdx.x;            // 256
    #pragma unroll
    for (int u = 0; u < 4; ++u) {
        int i = u * 256 + t;              // 0..1023
        int kd = i >> 8, kr = (i >> 4) & 15, kc = i & 15;
        float v = x[(size_t)(d * 4 + kd) * 65536 + (rr * 16 + kr) * 256 + (cc * 16 + kc)];
        p[(size_t)pi * 1024 + i] = f2bf(v);
    }
}

// ---------------- elementwise fp32 -> bf16 convert ----------------
__global__ void cvt_bf16_kernel(const float* __restrict__ in, unsigned short* __restrict__ out, int n4) {
    int i = blockIdx.x * 256 + threadIdx.x;
    if (i >= n4) return;
    float4 v = ((const float4*)in)[i];
    ushort4 o;
    o.x = f2bf(v.x); o.y = f2bf(v.y); o.z = f2bf(v.z); o.w = f2bf(v.w);
    ((ushort4*)out)[i] = o;
}

// ---------------- transpose + convert: in fp32 [R][C] -> out bf16 [C][R] ----------------
__global__ void transpose_cvt_kernel(const float* __restrict__ in, unsigned short* __restrict__ out,
                                     int R, int C) {
    __shared__ float t[32][33];
    const int tx = threadIdx.x & 31, ty = threadIdx.x >> 5;   // 32 x 8
    const int c0 = blockIdx.x * 32, r0 = blockIdx.y * 32;
    #pragma unroll
    for (int i = 0; i < 4; ++i)
        t[ty + i * 8][tx] = in[(size_t)(r0 + ty + i * 8) * C + c0 + tx];
    __syncthreads();
    #pragma unroll
    for (int i = 0; i < 4; ++i)
        out[(size_t)(c0 + ty + i * 8) * R + r0 + tx] = f2bf(t[tx][ty + i * 8]);
}

// 4x [768][768] transposes in one launch (z = which weight)
__global__ void transpose4_kernel(const float* __restrict__ wq, const float* __restrict__ wk,
                                  const float* __restrict__ wv, const float* __restrict__ wo,
                                  unsigned short* __restrict__ qkvT, unsigned short* __restrict__ oT) {
    __shared__ float t[32][33];
    const int z = blockIdx.z;
    const float* in = (z == 0) ? wq : (z == 1) ? wk : (z == 2) ? wv : wo;
    unsigned short* out = (z < 3) ? qkvT + (size_t)z * EMBED * EMBED : oT;
    const int tx = threadIdx.x & 31, ty = threadIdx.x >> 5;
    const int c0 = blockIdx.x * 32, r0 = blockIdx.y * 32;
    #pragma unroll
    for (int i = 0; i < 4; ++i)
        t[ty + i * 8][tx] = in[(size_t)(r0 + ty + i * 8) * EMBED + c0 + tx];
    __syncthreads();
    #pragma unroll
    for (int i = 0; i < 4; ++i)
        out[(size_t)(c0 + ty + i * 8) * EMBED + r0 + tx] = f2bf(t[tx][ty + i * 8]);
}

// ---------------- qkv bias concat (all layers) ----------------
__global__ void concat_bias_kernel(const float* __restrict__ bq, const float* __restrict__ bk,
                                   const float* __restrict__ bv, float* __restrict__ bqkv) {
    int i = blockIdx.x * 256 + threadIdx.x;
    if (i >= DEPTH * 2304) return;
    int L = i / 2304, j = i - L * 2304;
    float v = (j < 768) ? bq[L * 768 + j] : (j < 1536) ? bk[L * 768 + j - 768] : bv[L * 768 + j - 1536];
    bqkv[i] = v;
}

__global__ void cls_init_kernel(const float* __restrict__ cls,
                                const float* __restrict__ pos,
                                float* __restrict__ h) {
    int e = blockIdx.x * 256 + threadIdx.x;
    if (e < EMBED) h[e] = cls[e] + pos[e];
}

// ---------------- layernorm: one block per row, optional bf16 output ----------------
template<bool BF>
__global__ void ln_kernel(const float* __restrict__ in, void* __restrict__ outv,
                          const float* __restrict__ w, const float* __restrict__ b,
                          int M) {
    int row = blockIdx.x;
    if (row >= M) return;
    const float* xr = in + (size_t)row * EMBED;
    int tid = threadIdx.x;
    float v0 = xr[tid], v1 = xr[tid + 256], v2 = xr[tid + 512];
    __shared__ float red[4];
    float s = v0 + v1 + v2;
    #pragma unroll
    for (int o = 32; o > 0; o >>= 1) s += __shfl_down(s, o);
    if ((tid & 63) == 0) red[tid >> 6] = s;
    __syncthreads();
    float mean = (red[0] + red[1] + red[2] + red[3]) * (1.0f / 768.0f);
    __syncthreads();
    float d0 = v0 - mean, d1 = v1 - mean, d2 = v2 - mean;
    float q2 = d0 * d0 + d1 * d1 + d2 * d2;
    #pragma unroll
    for (int o = 32; o > 0; o >>= 1) q2 += __shfl_down(q2, o);
    if ((tid & 63) == 0) red[tid >> 6] = q2;
    __syncthreads();
    float var = (red[0] + red[1] + red[2] + red[3]) * (1.0f / 768.0f);
    float rstd = 1.0f / sqrtf(var + 1e-5f);
    float o0 = d0 * rstd * w[tid]       + b[tid];
    float o1 = d1 * rstd * w[tid + 256] + b[tid + 256];
    float o2 = d2 * rstd * w[tid + 512] + b[tid + 512];
    if (BF) {
        unsigned short* orow = (unsigned short*)outv + (size_t)row * EMBED;
        orow[tid] = f2bf(o0); orow[tid + 256] = f2bf(o1); orow[tid + 512] = f2bf(o2);
    } else {
        float* orow = (float*)outv + (size_t)row * EMBED;
        orow[tid] = o0; orow[tid + 256] = o1; orow[tid + 512] = o2;
    }
}

// ---------------- bf16 MFMA GEMM (m97 structure: global_load_lds staging) ----------------
// A: bf16 [M][K] rows padded to tile multiple, BT: bf16 [N][K].
// C = [C +] act(A@B + bias).  MODE: 0 store f32, 1 accum f32, 2 store bf16. ACT: 0 none, 1 gelu.
// 128x128 tile, BK=32, 256 threads = 4 waves, each wave a 64x64 sub-tile.
// LDS: linear [128 rows][4 k-octets of 16B]; global SOURCE k-octet pre-swizzled by
// (row>>1)&3, ds_read applies the same XOR -> 2-way (free) bank aliasing both sides.
template<int ACT, int MODE>
__global__ __launch_bounds__(256)
void gemm_bf16(const unsigned short* __restrict__ A, const unsigned short* __restrict__ BT,
               const float* __restrict__ bias, void* __restrict__ Cv,
               int M, int N, int K) {
    __shared__ unsigned short Al[128 * 32];
    __shared__ unsigned short Bl[128 * 32];
    const int tid = threadIdx.x;
    const int lane = tid & 63;
    const int w4 = tid >> 6;                  // wave id 0..3
    const int wm = w4 >> 1, wn = w4 & 1;
    const int row0 = blockIdx.y * 128, col0 = blockIdx.x * 128;

    f32x4 acc[4][4];
    #pragma unroll
    for (int mi = 0; mi < 4; ++mi)
        #pragma unroll
        for (int ni = 0; ni < 4; ++ni)
            #pragma unroll
            for (int j = 0; j < 4; ++j) acc[mi][ni][j] = 0.0f;

    // staging: wave w call j covers LDS chunks (w+j*4)*64 .. +63 (lane l -> chunk +l)
    // chunk c = row*4 + ko_lds ; holds global k-octet ko_lds ^ ((row>>1)&3)
    const int ksrc = (lane & 3) ^ ((lane >> 3) & 3);          // pre-swizzled source octet
    const int lrow_l = lane >> 2;                             // row within 16-row group
    // fragment read indices
    const int ln15 = lane & 15;
    const int kq = lane >> 4;
    const int kswz = (kq ^ ((ln15 >> 1) & 3)) * 8;
    const int arow_base = (wm * 64 + ln15) * 32 + kswz;
    const int brow_base = (wn * 64 + ln15) * 32 + kswz;

    for (int kt = 0; kt < K; kt += 32) {
        #pragma unroll
        for (int j = 0; j < 2; ++j) {
            const int g = w4 + j * 4;                         // 16-row group 0..7
            const int lrow = g * 16 + lrow_l;
            gload16(A  + (size_t)(row0 + lrow) * K + kt + ksrc * 8, &Al[g * 512]);
            gload16(BT + (size_t)(col0 + lrow) * K + kt + ksrc * 8, &Bl[g * 512]);
        }
        __syncthreads();   // drains vmcnt (loads landed) + barrier
        short8 af[4], bfr[4];
        #pragma unroll
        for (int mi = 0; mi < 4; ++mi)
            af[mi] = *(const short8*)&Al[arow_base + mi * 16 * 32];
        #pragma unroll
        for (int ni = 0; ni < 4; ++ni)
            bfr[ni] = *(const short8*)&Bl[brow_base + ni * 16 * 32];
        #pragma unroll
        for (int mi = 0; mi < 4; ++mi)
            #pragma unroll
            for (int ni = 0; ni < 4; ++ni)
                acc[mi][ni] = __builtin_amdgcn_mfma_f32_16x16x32_bf16(af[mi], bfr[ni], acc[mi][ni], 0, 0, 0);
        __syncthreads();   // all ds_reads done before next stage overwrites
    }

    float* Cf = (float*)Cv;
    unsigned short* Cb = (unsigned short*)Cv;
    #pragma unroll
    for (int mi = 0; mi < 4; ++mi) {
        #pragma unroll
        for (int ni = 0; ni < 4; ++ni) {
            const int col = col0 + wn * 64 + ni * 16 + ln15;
            const float bb = bias[col];
            #pragma unroll
            for (int j = 0; j < 4; ++j) {
                const int row = row0 + wm * 64 + mi * 16 + kq * 4 + j;
                if (row < M) {
                    float v = acc[mi][ni][j] + bb;
                    if (ACT == 1) v = 0.5f * v * (1.0f + erff(v * 0.70710678118654752f));
                    if (MODE == 0)      Cf[(size_t)row * N + col] = v;
                    else if (MODE == 1) Cf[(size_t)row * N + col] += v;
                    else                Cb[(size_t)row * N + col] = f2bf(v);
                }
            }
        }
    }
}

// ---------------- dilated attention (fp32 in from fused qkv, bf16 Obr out) ----------------
__global__ __launch_bounds__(256, 1)
void attn_kernel(const float* __restrict__ qkv,
                 unsigned short* __restrict__ Obr, float* __restrict__ Lbr) {
    const int bx = blockIdx.x, hh = blockIdx.y;
    int b, n;
    if      (bx < 17) { b = 0; n = bx; }
    else if (bx < 26) { b = 1; n = bx - 17; }
    else if (bx < 31) { b = 2; n = bx - 26; }
    else if (bx < 34) { b = 3; n = bx - 31; }
    else              { b = 4; n = bx - 34; }
    const int r = 1 << b;
    const int w = 128 << b;
    const int hb = hh & (r - 1);
    const int base = n * w + hb;

    __shared__ float ks[128][64];
    __shared__ float vs[128][64];
    const int tid = threadIdx.x;
    {
        int j = tid >> 1, hf = tid & 1;
        int pos = base + r * j;
        float4* kd = (float4*)&ks[j][hf * 32];
        float4* vd = (float4*)&vs[j][hf * 32];
        if (pos < N_REAL) {
            const float* kp = qkv + (size_t)pos * 2304 + 768  + hh * 64 + hf * 32;
            const float* vp = qkv + (size_t)pos * 2304 + 1536 + hh * 64 + hf * 32;
            #pragma unroll
            for (int u = 0; u < 8; ++u) { kd[u] = ((const float4*)kp)[u]; vd[u] = ((const float4*)vp)[u]; }
        } else {
            float4 z = make_float4(0.f, 0.f, 0.f, 0.f);
            #pragma unroll
            for (int u = 0; u < 8; ++u) { kd[u] = z; vd[u] = z; }
        }
    }
    __syncthreads();

    const int qi = tid >> 1, hf = tid & 1;
    const int qpos = base + r * qi;

    float qr[64];
    if (qpos < N_REAL) {
        const float4* qs = (const float4*)(qkv + (size_t)qpos * 2304 + hh * 64);
        #pragma unroll
        for (int u = 0; u < 16; ++u) {
            float4 t = qs[u];
            qr[4*u] = t.x; qr[4*u+1] = t.y; qr[4*u+2] = t.z; qr[4*u+3] = t.w;
        }
    } else {
        #pragma unroll
        for (int u = 0; u < 64; ++u) qr[u] = 0.f;
    }

    float s[64];
    const float scale = 0.125f;
    #pragma unroll
    for (int jj = 0; jj < 64; ++jj) {
        const int key = hf * 64 + jj;
        const int kpos = base + r * key;
        float acc = 0.f;
        const float4* kr4 = (const float4*)&ks[key][0];
        #pragma unroll
        for (int u = 0; u < 16; ++u) {
            float4 t = kr4[u];
            acc += qr[4*u] * t.x + qr[4*u+1] * t.y + qr[4*u+2] * t.z + qr[4*u+3] * t.w;
        }
        s[jj] = (kpos < N_REAL) ? acc * scale : NEGV;
    }
    float m = NEGV;
    #pragma unroll
    for (int jj = 0; jj < 64; ++jj) m = fmaxf(m, s[jj]);
    m = fmaxf(m, __shfl_xor(m, 1));
    float sum = 0.f;
    #pragma unroll
    for (int jj = 0; jj < 64; ++jj) { s[jj] = expf(s[jj] - m); sum += s[jj]; }
    sum += __shfl_xor(sum, 1);
    float o[64];
    #pragma unroll
    for (int u = 0; u < 64; ++u) o[u] = 0.f;
    #pragma unroll
    for (int jj = 0; jj < 64; ++jj) {
        const int key = hf * 64 + jj;
        const float p = s[jj];
        const float4* vr4 = (const float4*)&vs[key][0];
        #pragma unroll
        for (int u = 0; u < 16; ++u) {
            float4 t = vr4[u];
            o[4*u]   += p * t.x;
            o[4*u+1] += p * t.y;
            o[4*u+2] += p * t.z;
            o[4*u+3] += p * t.w;
        }
    }
    #pragma unroll
    for (int u = 0; u < 64; ++u) o[u] += __shfl_xor(o[u], 1);

    if (hf == 0 && qpos < N_REAL) {
        float inv = 1.0f / sum;
        unsigned short* od = Obr + ((size_t)b * N_REAL + qpos) * EMBED + hh * 64;
        #pragma unroll
        for (int u = 0; u < 64; ++u) od[u] = f2bf(o[u] * inv);
        Lbr[((size_t)b * SP + qpos) * HEADS + hh] = m + logf(sum);
    }
}

// ---------------- branch combine -> bf16 (validity derived, no fill needed) ----------------
__global__ void combine_kernel(const unsigned short* __restrict__ Obr, const float* __restrict__ Lbr,
                               unsigned short* __restrict__ out) {
    int gid = blockIdx.x * 256 + threadIdx.x;
    if (gid >= N_REAL * EMBED) return;
    int p = gid / EMBED, e = gid - p * EMBED;
    int h = e >> 6;
    float l[5];
    float mx = NEGV;
    #pragma unroll
    for (int b = 0; b < 5; ++b) {
        const int rm = (1 << b) - 1;
        l[b] = ((p & rm) == (h & rm)) ? Lbr[((size_t)b * SP + p) * HEADS + h] : NEGV;
        mx = fmaxf(mx, l[b]);
    }
    float wsum = 0.f, acc = 0.f;
    #pragma unroll
    for (int b = 0; b < 5; ++b) {
        if (l[b] > NEGV * 0.5f) {
            float wt = expf(l[b] - mx);
            wsum += wt;
            acc += wt * bf2f(Obr[((size_t)b * N_REAL + p) * EMBED + e]);
        }
    }
    out[(size_t)p * EMBED + e] = f2bf(acc / wsum);
}

// ---------------- host orchestration ----------------
extern "C" void kernel_launch(void* const* d_in, const int* in_sizes, int n_in,
                              void* d_out, int out_size, void* d_ws, size_t ws_size,
                              hipStream_t stream) {
    const float* x      = (const float*)d_in[0];
    const float* conv_w = (const float*)d_in[1];
    const float* conv_b = (const float*)d_in[2];
    const float* cls    = (const float*)d_in[3];
    const float* pos    = (const float*)d_in[4];
    const float* ln1w   = (const float*)d_in[5];
    const float* ln1b   = (const float*)d_in[6];
    const float* wq     = (const float*)d_in[7];
    const float* bq     = (const float*)d_in[8];
    const float* wk     = (const float*)d_in[9];
    const float* bk     = (const float*)d_in[10];
    const float* wv     = (const float*)d_in[11];
    const float* bv     = (const float*)d_in[12];
    const float* wo     = (const float*)d_in[13];
    const float* bo     = (const float*)d_in[14];
    const float* ln2w   = (const float*)d_in[15];
    const float* ln2b   = (const float*)d_in[16];
    const float* w1     = (const float*)d_in[17];
    const float* b1     = (const float*)d_in[18];
    const float* w2     = (const float*)d_in[19];
    const float* b2     = (const float*)d_in[20];
    const float* lnfw   = (const float*)d_in[21];
    const float* lnfb   = (const float*)d_in[22];

    float* ws = (float*)d_ws;
    // fp32 buffers
    float* h     = ws;  ws += (size_t)SP * EMBED;            // residual stream
    float* qkv   = ws;  ws += (size_t)SP * 2304;             // fused q|k|v
    float* Lbr   = ws;  ws += (size_t)5 * SP * HEADS;
    float* bqkv  = ws;  ws += (size_t)DEPTH * 2304;
    // bf16 buffers (ushort)
    unsigned short* xln_bf   = (unsigned short*)ws;  ws += (size_t)SPAD * EMBED / 2;
    unsigned short* attn_bf  = (unsigned short*)ws;  ws += (size_t)SPAD * EMBED / 2;
    unsigned short* mid_bf   = (unsigned short*)ws;  ws += (size_t)SPAD * MLP_DIM / 2;
    unsigned short* patch_bf = (unsigned short*)ws;  ws += (size_t)2048 * 1024 / 2;
    unsigned short* convwT   = (unsigned short*)ws;  ws += (size_t)EMBED * 1024 / 2;
    unsigned short* Obr      = (unsigned short*)ws;  ws += (size_t)5 * N_REAL * EMBED / 2 + 64;
    unsigned short* wqkvT    = (unsigned short*)ws;  ws += (size_t)2304 * EMBED / 2;
    unsigned short* woT      = (unsigned short*)ws;  ws += (size_t)EMBED * EMBED / 2;
    unsigned short* w1T      = (unsigned short*)ws;  ws += (size_t)MLP_DIM * EMBED / 2;
    unsigned short* w2T      = (unsigned short*)ws;  ws += (size_t)EMBED * MLP_DIM / 2;

    // ---- embed ----
    im2col_kernel<<<2048, 256, 0, stream>>>(x, patch_bf);
    cvt_bf16_kernel<<<(EMBED * 1024 / 4 + 255) / 256, 256, 0, stream>>>(conv_w, convwT, EMBED * 1024 / 4);
    concat_bias_kernel<<<(DEPTH * 2304 + 255) / 256, 256, 0, stream>>>(bq, bk, bv, bqkv);
    cls_init_kernel<<<3, 256, 0, stream>>>(cls, pos, h);
    hipMemcpyAsync(h + EMBED, pos + EMBED, (size_t)2048 * EMBED * sizeof(float),
                   hipMemcpyDeviceToDevice, stream);
    // patch GEMM: h(rows 1..2048) += patches @ conv_w^T + conv_b
    gemm_bf16<0, 1><<<dim3(6, 16), 256, 0, stream>>>(patch_bf, convwT, conv_b,
                                                     h + EMBED, 2048, EMBED, 1024);

    for (int L = 0; L < DEPTH; ++L) {
        const size_t EE = (size_t)EMBED * EMBED;
        const size_t EM = (size_t)EMBED * MLP_DIM;
        // weight transposes for this layer (wq/wk/wv/wo fused into one launch)
        transpose4_kernel<<<dim3(24, 24, 4), 256, 0, stream>>>(wq + L * EE, wk + L * EE,
                                                               wv + L * EE, wo + L * EE,
                                                               wqkvT, woT);
        transpose_cvt_kernel<<<dim3(96, 24), 256, 0, stream>>>(w1 + L * EM, w1T, EMBED, MLP_DIM);
        transpose_cvt_kernel<<<dim3(24, 96), 256, 0, stream>>>(w2 + L * EM, w2T, MLP_DIM, EMBED);

        // LN1 -> bf16
        ln_kernel<true><<<N_REAL, 256, 0, stream>>>(h, xln_bf, ln1w + (size_t)L * EMBED,
                                                    ln1b + (size_t)L * EMBED, N_REAL);
        // fused QKV
        gemm_bf16<0, 0><<<dim3(18, 17), 256, 0, stream>>>(xln_bf, wqkvT, bqkv + (size_t)L * 2304,
                                                          qkv, N_REAL, 2304, EMBED);
        // dilated attention
        attn_kernel<<<dim3(36, 12), 256, 0, stream>>>(qkv, Obr, Lbr);
        combine_kernel<<<((N_REAL * EMBED) + 255) / 256, 256, 0, stream>>>(Obr, Lbr, attn_bf);
        // O-projection + residual
        gemm_bf16<0, 1><<<dim3(6, 17), 256, 0, stream>>>(attn_bf, woT, bo + (size_t)L * EMBED,
                                                         h, N_REAL, EMBED, EMBED);
        // LN2 + MLP + residual
        ln_kernel<true><<<N_REAL, 256, 0, stream>>>(h, xln_bf, ln2w + (size_t)L * EMBED,
                                                    ln2b + (size_t)L * EMBED, N_REAL);
        gemm_bf16<1, 2><<<dim3(24, 17), 256, 0, stream>>>(xln_bf, w1T, b1 + (size_t)L * MLP_DIM,
                                                          mid_bf, N_REAL, MLP_DIM, EMBED);
        gemm_bf16<0, 1><<<dim3(6, 17), 256, 0, stream>>>(mid_bf, w2T, b2 + (size_t)L * EMBED,
                                                         h, N_REAL, EMBED, MLP_DIM);
    }

    // final LN on row 0 -> d_out (768 fp32)
    ln_kernel<false><<<1, 256, 0, stream>>>(h, (float*)d_out, lnfw, lnfb, 1);
}